// Round 1
// baseline (264.062 us; speedup 1.0000x reference)
//
#include <hip/hip_runtime.h>
#include <math.h>

#define IMG_H 512
#define IMG_W 512
#define TILE  32
#define RAD   5
#define KS    11
#define SP_H  42          // TILE + 2*RAD
#define SP_W  44          // padded to multiple of 4 for float4 LDS reads
#define HT_W  44          // 42 rows, padded to 44

__global__ __launch_bounds__(256)
void ssim_main(const float* __restrict__ pred, const float* __restrict__ targ,
               double* __restrict__ acc)
{
    __shared__ float sp[SP_H][SP_W];
    __shared__ float st[SP_H][SP_W];
    __shared__ float hT[5][TILE][HT_W];   // transposed horizontal sums: [quantity][out_col][row]
    __shared__ float red[4];

    const int tid = threadIdx.x;
    const int tx = blockIdx.x, ty = blockIdx.y, img = blockIdx.z;
    const float* __restrict__ p = pred + (size_t)img * (IMG_H * IMG_W);
    const float* __restrict__ t = targ + (size_t)img * (IMG_H * IMG_W);
    const int gr0 = ty * TILE - RAD;
    const int gc0 = tx * TILE - RAD;

    // --- normalized separable Gaussian weights (matches jnp: exp(-d^2/(2*1.5^2)) / sum) ---
    float wn[KS];
    {
        float s = 0.f;
        #pragma unroll
        for (int i = 0; i < KS; ++i) {
            float d = (float)(i - RAD);
            wn[i] = expf(-d * d * (1.0f / 4.5f));
            s += wn[i];
        }
        float inv = 1.0f / s;
        #pragma unroll
        for (int i = 0; i < KS; ++i) wn[i] *= inv;
    }

    // --- Stage A: load 42x42 halo tiles (zero padding outside image, like SAME conv) ---
    for (int i = tid; i < SP_H * 42; i += 256) {
        int r = i / 42, c = i % 42;
        int gr = gr0 + r, gc = gc0 + c;
        float pv = 0.f, tv = 0.f;
        if (gr >= 0 && gr < IMG_H && gc >= 0 && gc < IMG_W) {
            size_t idx = (size_t)gr * IMG_W + gc;
            pv = p[idx];
            tv = t[idx];
        }
        sp[r][c] = pv;
        st[r][c] = tv;
    }
    __syncthreads();

    // --- Stage B: horizontal 11-tap pass for 5 quantities, 4 outputs/thread, store transposed ---
    // item space: 42 rows x 8 col-groups = 336
    for (int i = tid; i < 42 * 8; i += 256) {
        int r  = i % 42;        // consecutive lanes vary r -> low-conflict transposed writes
        int c0 = (i / 42) * 4;
        float pr[16], tr[16];
        #pragma unroll
        for (int v = 0; v < 4; ++v) {
            *(float4*)&pr[v * 4] = *(const float4*)&sp[r][c0 + v * 4];
            *(float4*)&tr[v * 4] = *(const float4*)&st[r][c0 + v * 4];
        }
        #pragma unroll
        for (int j = 0; j < 4; ++j) {
            float hp = 0.f, ht_ = 0.f, hpp = 0.f, htt = 0.f, hpt = 0.f;
            #pragma unroll
            for (int k = 0; k < KS; ++k) {
                float pv = pr[j + k], tv = tr[j + k];
                float w = wn[k];
                float wp = w * pv;
                float wt = w * tv;
                hp  += wp;
                ht_ += wt;
                hpp += wp * pv;
                htt += wt * tv;
                hpt += wp * tv;
            }
            hT[0][c0 + j][r] = hp;
            hT[1][c0 + j][r] = ht_;
            hT[2][c0 + j][r] = hpp;
            hT[3][c0 + j][r] = htt;
            hT[4][c0 + j][r] = hpt;
        }
    }
    __syncthreads();

    // --- Stage C: vertical 11-tap pass (vectorized along transposed rows), SSIM, local sum ---
    float lsum = 0.f;
    {
        const int c  = tid >> 3;          // output column 0..31
        const int r0 = (tid & 7) * 4;     // output row group base 0..28
        float accv[5][4];
        #pragma unroll
        for (int q = 0; q < 5; ++q) {
            float h[16];
            #pragma unroll
            for (int v = 0; v < 4; ++v)
                *(float4*)&h[v * 4] = *(const float4*)&hT[q][c][r0 + v * 4];
            #pragma unroll
            for (int j = 0; j < 4; ++j) {
                float s = 0.f;
                #pragma unroll
                for (int k = 0; k < KS; ++k) s += wn[k] * h[j + k];
                accv[q][j] = s;
            }
        }
        const float C1 = 1e-4f, C2 = 9e-4f;
        #pragma unroll
        for (int j = 0; j < 4; ++j) {
            float mp = accv[0][j], mt = accv[1][j];
            float vp = accv[2][j] - mp * mp;
            float vt = accv[3][j] - mt * mt;
            float cv = accv[4][j] - mp * mt;
            float num = (2.f * mp * mt + C1) * (2.f * cv + C2);
            float den = (mp * mp + mt * mt + C1) * (vp + vt + C2);
            lsum += num / den;
        }
    }

    // --- Stage D: block reduction + one double atomic per block ---
    #pragma unroll
    for (int off = 32; off > 0; off >>= 1)
        lsum += __shfl_down(lsum, off, 64);
    int wave = tid >> 6;
    if ((tid & 63) == 0) red[wave] = lsum;
    __syncthreads();
    if (tid == 0) {
        float bs = red[0] + red[1] + red[2] + red[3];
        atomicAdd(acc, (double)bs);
    }
}

__global__ void ssim_init(double* acc)
{
    if (threadIdx.x == 0) *acc = 0.0;
}

__global__ void ssim_fin(const double* __restrict__ acc, float* __restrict__ out,
                         double inv_n)
{
    if (threadIdx.x == 0) out[0] = (float)(1.0 - (*acc) * inv_n);
}

extern "C" void kernel_launch(void* const* d_in, const int* in_sizes, int n_in,
                              void* d_out, int out_size, void* d_ws, size_t ws_size,
                              hipStream_t stream)
{
    const float* pred = (const float*)d_in[0];
    const float* targ = (const float*)d_in[1];
    float* out  = (float*)d_out;
    double* acc = (double*)d_ws;

    const long long total = (long long)in_sizes[0];           // 16*3*512*512
    const int n_img = (int)(total / (IMG_H * IMG_W));         // 48 depthwise planes

    hipLaunchKernelGGL(ssim_init, dim3(1), dim3(1), 0, stream, acc);
    dim3 grid(IMG_W / TILE, IMG_H / TILE, n_img);
    hipLaunchKernelGGL(ssim_main, grid, dim3(256), 0, stream, pred, targ, acc);
    hipLaunchKernelGGL(ssim_fin, dim3(1), dim3(1), 0, stream, acc, out,
                       1.0 / (double)total);
}